// Round 1
// baseline (409.999 us; speedup 1.0000x reference)
//
#include <hip/hip_runtime.h>
#include <math.h>

constexpr int BATCH = 32;
constexpr int QL = 1024;
constexpr int KL = 1024;
constexpr int D = 128;
constexpr int BQ = 64;   // query rows per block
constexpr int BK = 32;   // key rows per tile
constexpr int DP = 132;  // padded D (132*4B row pitch, 16B aligned, breaks bank stride)
constexpr int SP = 33;   // padded BK for score tile

__global__ __launch_bounds__(256, 2)
void attn_fwd(const float* __restrict__ Qp, const float* __restrict__ Kp,
              const float* __restrict__ Vp, const int* __restrict__ VLp,
              float* __restrict__ Op) {
  __shared__ float sQ[BQ][DP];
  __shared__ float sK[BK][DP];
  __shared__ float sV[BK][DP];
  __shared__ float sS[BQ][SP];
  __shared__ float sM[BQ];
  __shared__ float sL[BQ];
  __shared__ float sA[BQ];

  const int b   = blockIdx.y;
  const int qt  = blockIdx.x;
  const int tid = threadIdx.x;
  const int vl  = VLp[b];

  const float* Qb = Qp + ((size_t)(b * QL + qt * BQ)) * D;
  const float* Kb = Kp + (size_t)b * KL * D;
  const float* Vb = Vp + (size_t)b * KL * D;

  // ---- stage Q tile: 64x128 floats = 2048 float4, 8 per thread, coalesced
  #pragma unroll
  for (int i = 0; i < 8; ++i) {
    int f = tid + i * 256;
    int row = f >> 5, c4 = f & 31;
    float4 v = reinterpret_cast<const float4*>(Qb)[f];
    *reinterpret_cast<float4*>(&sQ[row][c4 * 4]) = v;
  }
  if (tid < BQ) { sM[tid] = -INFINITY; sL[tid] = 0.0f; }

  // O accumulator: thread (rg = tid>>5) owns rows rg*8..rg*8+7, cols dc*4..dc*4+3
  float acc[8][4];
  #pragma unroll
  for (int r = 0; r < 8; ++r)
    acc[r][0] = acc[r][1] = acc[r][2] = acc[r][3] = 0.0f;

  const int tx = tid & 15;   // key group (2 keys each)
  const int ty = tid >> 4;   // row group (4 rows each)
  const int dc = tid & 31;   // d-column float4 group
  const int rg = tid >> 5;   // row group of 8 for PV phase

  // masked keys contribute exp(-1e6 - m) == 0.0f exactly -> skip whole tiles
  const int ntiles = (vl + BK - 1) / BK;
  const float scale = 0.088388347648318447f;  // 1/sqrt(128)

  for (int t = 0; t < ntiles; ++t) {
    __syncthreads();  // previous iteration done with sK/sV/sS

    // ---- stage K,V tiles: 32x128 floats = 1024 float4 each, 4 per thread
    const float4* Kt = reinterpret_cast<const float4*>(Kb + (size_t)t * BK * D);
    const float4* Vt = reinterpret_cast<const float4*>(Vb + (size_t)t * BK * D);
    #pragma unroll
    for (int i = 0; i < 4; ++i) {
      int f = tid + i * 256;
      int row = f >> 5, c4 = f & 31;
      *reinterpret_cast<float4*>(&sK[row][c4 * 4]) = Kt[f];
      *reinterpret_cast<float4*>(&sV[row][c4 * 4]) = Vt[f];
    }
    __syncthreads();

    // ---- S = Q K^T (4 rows x 2 keys per thread), fp32 vector FMA
    float s[4][2];
    #pragma unroll
    for (int r = 0; r < 4; ++r) s[r][0] = s[r][1] = 0.0f;
    #pragma unroll 8
    for (int d = 0; d < D; d += 4) {
      float4 q[4], k[2];
      #pragma unroll
      for (int r = 0; r < 4; ++r)
        q[r] = *reinterpret_cast<const float4*>(&sQ[ty * 4 + r][d]);
      #pragma unroll
      for (int c = 0; c < 2; ++c)
        k[c] = *reinterpret_cast<const float4*>(&sK[tx * 2 + c][d]);
      #pragma unroll
      for (int r = 0; r < 4; ++r)
        #pragma unroll
        for (int c = 0; c < 2; ++c)
          s[r][c] += q[r].x * k[c].x + q[r].y * k[c].y +
                     q[r].z * k[c].z + q[r].w * k[c].w;
    }
    #pragma unroll
    for (int r = 0; r < 4; ++r)
      #pragma unroll
      for (int c = 0; c < 2; ++c) {
        int kg = t * BK + tx * 2 + c;
        sS[ty * 4 + r][tx * 2 + c] = (kg < vl) ? s[r][c] * scale : -1.0e6f;
      }
    __syncthreads();

    // ---- online softmax update, one thread per row (conflict-free: SP=33)
    if (tid < BQ) {
      const int row = tid;
      float mold = sM[row];
      float tmax = -INFINITY;
      #pragma unroll 8
      for (int j = 0; j < BK; ++j) tmax = fmaxf(tmax, sS[row][j]);
      float mnew  = fmaxf(mold, tmax);
      float alpha = __expf(mold - mnew);   // exp(-inf)=0 on first tile
      float lsum  = 0.0f;
      #pragma unroll 8
      for (int j = 0; j < BK; ++j) {
        float p = __expf(sS[row][j] - mnew);
        sS[row][j] = p;
        lsum += p;
      }
      sL[row] = sL[row] * alpha + lsum;
      sM[row] = mnew;
      sA[row] = alpha;
    }
    __syncthreads();

    // ---- O = O*alpha + P V   (rows rg*8..+7, cols dc*4..+3 per thread)
    #pragma unroll
    for (int r = 0; r < 8; ++r) {
      float a = sA[rg * 8 + r];
      acc[r][0] *= a; acc[r][1] *= a; acc[r][2] *= a; acc[r][3] *= a;
    }
    #pragma unroll 8
    for (int j = 0; j < BK; ++j) {
      float4 v4 = *reinterpret_cast<const float4*>(&sV[j][dc * 4]);
      #pragma unroll
      for (int r = 0; r < 8; ++r) {
        float p = sS[rg * 8 + r][j];   // broadcast across 32 lanes of same rg
        acc[r][0] += p * v4.x; acc[r][1] += p * v4.y;
        acc[r][2] += p * v4.z; acc[r][3] += p * v4.w;
      }
    }
  }

  // ---- epilogue: divide by l, coalesced float4 stores
  float* Ob = Op + ((size_t)(b * QL + qt * BQ)) * D;
  #pragma unroll
  for (int r = 0; r < 8; ++r) {
    int row = rg * 8 + r;
    float inv = 1.0f / sL[row];
    float4 o;
    o.x = acc[r][0] * inv; o.y = acc[r][1] * inv;
    o.z = acc[r][2] * inv; o.w = acc[r][3] * inv;
    *reinterpret_cast<float4*>(&Ob[(size_t)row * D + dc * 4]) = o;
  }
}

extern "C" void kernel_launch(void* const* d_in, const int* in_sizes, int n_in,
                              void* d_out, int out_size, void* d_ws, size_t ws_size,
                              hipStream_t stream) {
  const float* Qp = (const float*)d_in[0];
  const float* Kp = (const float*)d_in[1];
  const float* Vp = (const float*)d_in[2];
  const int*   VL = (const int*)d_in[3];
  float* Op = (float*)d_out;

  dim3 grid(QL / BQ, BATCH);
  attn_fwd<<<grid, dim3(256), 0, stream>>>(Qp, Kp, Vp, VL, Op);
}

// Round 2
// 141.256 us; speedup vs baseline: 2.9025x; 2.9025x over previous
//
#include <hip/hip_runtime.h>
#include <math.h>

typedef _Float16 f16;
typedef __attribute__((ext_vector_type(8))) _Float16 f16x8;
typedef __attribute__((ext_vector_type(4))) _Float16 f16x4;
typedef __attribute__((ext_vector_type(4))) float f32x4;

constexpr int BATCH = 32;
constexpr int QL = 1024;
constexpr int KL = 1024;
constexpr int D = 128;
constexpr int BQ = 64;    // query rows per block (16 per wave)
constexpr int BK = 64;    // key rows per tile
constexpr int DKP = 136;  // sK row pitch in halves (272 B: 16B-aligned, ≡16 mod 128)
constexpr int BKP = 72;   // sVT/sP row pitch in halves (144 B)

// scale * log2(e): softmax computed in exp2 domain
#define CSC 0.12752863187087177f

__global__ __launch_bounds__(256, 3)
void attn_fwd(const float* __restrict__ Qp, const float* __restrict__ Kp,
              const float* __restrict__ Vp, const int* __restrict__ VLp,
              float* __restrict__ Op) {
  __shared__ f16 sK[BK][DKP];    // K tile   [kk][d]
  __shared__ f16 sVT[D][BKP];    // V tile transposed [d][kk]
  __shared__ f16 sP[4][16][BKP]; // per-wave P tile [row][kk]

  const int tid  = threadIdx.x;
  const int wave = tid >> 6, lane = tid & 63;
  const int l16  = lane & 15, quad = lane >> 4;
  const int b = blockIdx.y, qt = blockIdx.x;
  const int vl = VLp[b];

  // ---- Q fragments (A-operand layout), kept in registers for all K tiles.
  // A[m = l16][k = quad*8 + j], row = qt*64 + wave*16 + l16
  const float* Qb = Qp + ((size_t)(b * QL + qt * BQ + wave * 16 + l16)) * D;
  f16x8 qfrag[4];
  #pragma unroll
  for (int kc = 0; kc < 4; ++kc) {
    const float* p = Qb + kc * 32 + quad * 8;
    float4 u = *(const float4*)p;
    float4 v = *(const float4*)(p + 4);
    f16x8 f;
    f[0] = (f16)u.x; f[1] = (f16)u.y; f[2] = (f16)u.z; f[3] = (f16)u.w;
    f[4] = (f16)v.x; f[5] = (f16)v.y; f[6] = (f16)v.z; f[7] = (f16)v.w;
    qfrag[kc] = f;
  }

  // online-softmax state per owned row (row = quad*4 + r), log2 domain
  float m2[4] = {-INFINITY, -INFINITY, -INFINITY, -INFINITY};
  float lsum[4] = {0.f, 0.f, 0.f, 0.f};
  f32x4 o[8];
  #pragma unroll
  for (int dt = 0; dt < 8; ++dt) o[dt] = (f32x4){0.f, 0.f, 0.f, 0.f};

  const float* Kb = Kp + (size_t)b * KL * D;
  const float* Vb = Vp + (size_t)b * KL * D;
  const int ntiles = (vl + BK - 1) / BK;  // masked tiles contribute exactly 0

  for (int t = 0; t < ntiles; ++t) {
    __syncthreads();  // all waves done reading previous sK/sVT

    // ---- stage K tile: 64x128 fp32 -> fp16 LDS, coalesced reads
    {
      const float4* Kt = (const float4*)(Kb + (size_t)t * BK * D);
      #pragma unroll
      for (int i = 0; i < 8; ++i) {
        int f = tid + i * 256;
        int row = f >> 5, c4 = f & 31;
        float4 u = Kt[f];
        f16x4 h;
        h[0] = (f16)u.x; h[1] = (f16)u.y; h[2] = (f16)u.z; h[3] = (f16)u.w;
        *(f16x4*)&sK[row][c4 * 4] = h;
      }
      // ---- stage V tile TRANSPOSED: lanes vary along kk => LDS writes 2-way (free)
      const float* Vt = Vb + (size_t)t * BK * D;
      #pragma unroll
      for (int i = 0; i < 2; ++i) {
        int f = tid + i * 256;       // 0..511
        int rq = f & 15;             // kk quad  (kk = rq*4 .. rq*4+3)
        int c4 = f >> 4;             // d chunk  (d = c4*4 .. c4*4+3)
        const float* base = Vt + (size_t)(rq * 4) * D + c4 * 4;
        float4 r0 = *(const float4*)(base);
        float4 r1 = *(const float4*)(base + D);
        float4 r2 = *(const float4*)(base + 2 * D);
        float4 r3 = *(const float4*)(base + 3 * D);
        int d0 = c4 * 4, k0 = rq * 4;
        f16x4 h;
        h[0] = (f16)r0.x; h[1] = (f16)r1.x; h[2] = (f16)r2.x; h[3] = (f16)r3.x;
        *(f16x4*)&sVT[d0 + 0][k0] = h;
        h[0] = (f16)r0.y; h[1] = (f16)r1.y; h[2] = (f16)r2.y; h[3] = (f16)r3.y;
        *(f16x4*)&sVT[d0 + 1][k0] = h;
        h[0] = (f16)r0.z; h[1] = (f16)r1.z; h[2] = (f16)r2.z; h[3] = (f16)r3.z;
        *(f16x4*)&sVT[d0 + 2][k0] = h;
        h[0] = (f16)r0.w; h[1] = (f16)r1.w; h[2] = (f16)r2.w; h[3] = (f16)r3.w;
        *(f16x4*)&sVT[d0 + 3][k0] = h;
      }
    }
    __syncthreads();

    // ---- S = Q K^T : 4 col-tiles x 4 k-steps of 16x16x32 MFMA
    f32x4 s[4];
    #pragma unroll
    for (int ct = 0; ct < 4; ++ct) {
      f32x4 c = (f32x4){0.f, 0.f, 0.f, 0.f};
      #pragma unroll
      for (int kc = 0; kc < 4; ++kc) {
        f16x8 kf = *(const f16x8*)&sK[ct * 16 + l16][kc * 32 + quad * 8];
        c = __builtin_amdgcn_mfma_f32_16x16x32_f16(qfrag[kc], kf, c, 0, 0, 0);
      }
      s[ct] = c;
    }

    // ---- scale into log2 domain + key-padding mask (lane-uniform per ct)
    #pragma unroll
    for (int ct = 0; ct < 4; ++ct) {
      int kk = t * BK + ct * 16 + l16;
      bool ok = kk < vl;
      #pragma unroll
      for (int r = 0; r < 4; ++r)
        s[ct][r] = ok ? s[ct][r] * CSC : -1.0e9f;
    }

    // ---- online softmax: each 16-lane group fully owns rows quad*4+r
    float mnew[4], alpha[4], ls[4];
    #pragma unroll
    for (int r = 0; r < 4; ++r) {
      float v = fmaxf(fmaxf(s[0][r], s[1][r]), fmaxf(s[2][r], s[3][r]));
      v = fmaxf(v, __shfl_xor(v, 1));
      v = fmaxf(v, __shfl_xor(v, 2));
      v = fmaxf(v, __shfl_xor(v, 4));
      v = fmaxf(v, __shfl_xor(v, 8));
      mnew[r]  = fmaxf(m2[r], v);
      alpha[r] = __builtin_amdgcn_exp2f(m2[r] - mnew[r]);  // exp2(-inf)=0 first tile
      m2[r]    = mnew[r];
      ls[r]    = 0.f;
    }
    #pragma unroll
    for (int ct = 0; ct < 4; ++ct)
      #pragma unroll
      for (int r = 0; r < 4; ++r) {
        float p = __builtin_amdgcn_exp2f(s[ct][r] - mnew[r]);  // masked -> 0 exactly
        s[ct][r] = p;
        ls[r] += p;
      }
    #pragma unroll
    for (int r = 0; r < 4; ++r) {
      float v = ls[r];
      v += __shfl_xor(v, 1);
      v += __shfl_xor(v, 2);
      v += __shfl_xor(v, 4);
      v += __shfl_xor(v, 8);
      lsum[r] = lsum[r] * alpha[r] + v;
    }

    // ---- P -> LDS (fp16) in A-operand readable layout; rescale O by alpha
    #pragma unroll
    for (int ct = 0; ct < 4; ++ct)
      #pragma unroll
      for (int r = 0; r < 4; ++r)
        sP[wave][quad * 4 + r][ct * 16 + l16] = (f16)s[ct][r];
    #pragma unroll
    for (int dt = 0; dt < 8; ++dt)
      #pragma unroll
      for (int r = 0; r < 4; ++r)
        o[dt][r] *= alpha[r];

    // sP is wave-private: in-wave DS ordering + waitcnt suffices (no barrier)
    asm volatile("s_waitcnt lgkmcnt(0)" ::: "memory");

    // ---- O += P V : A = P (16x64), B = V^T-staged (k=kk contiguous)
    #pragma unroll
    for (int ks = 0; ks < 2; ++ks) {
      f16x8 pf = *(const f16x8*)&sP[wave][l16][ks * 32 + quad * 8];
      #pragma unroll
      for (int dt = 0; dt < 8; ++dt) {
        f16x8 vf = *(const f16x8*)&sVT[dt * 16 + l16][ks * 32 + quad * 8];
        o[dt] = __builtin_amdgcn_mfma_f32_16x16x32_f16(pf, vf, o[dt], 0, 0, 0);
      }
    }
  }

  // ---- epilogue: O /= l, store (C-layout scatter; 64B segments per 16 lanes)
  float* Ob = Op + ((size_t)(b * QL + qt * BQ + wave * 16)) * D;
  #pragma unroll
  for (int r = 0; r < 4; ++r) {
    float inv = 1.0f / lsum[r];
    int row = quad * 4 + r;
    #pragma unroll
    for (int dt = 0; dt < 8; ++dt)
      Ob[(size_t)row * D + dt * 16 + l16] = o[dt][r] * inv;
  }
}

extern "C" void kernel_launch(void* const* d_in, const int* in_sizes, int n_in,
                              void* d_out, int out_size, void* d_ws, size_t ws_size,
                              hipStream_t stream) {
  const float* Qp = (const float*)d_in[0];
  const float* Kp = (const float*)d_in[1];
  const float* Vp = (const float*)d_in[2];
  const int*   VL = (const int*)d_in[3];
  float* Op = (float*)d_out;

  dim3 grid(QL / BQ, BATCH);
  attn_fwd<<<grid, dim3(256), 0, stream>>>(Qp, Kp, Vp, VL, Op);
}